// Round 2
// baseline (526.373 us; speedup 1.0000x reference)
//
#include <hip/hip_runtime.h>

#define N_NODES 20000
#define N_EDGES 320000
#define NBINS   (4*N_NODES)
#define SCAN_NBLK 313

typedef unsigned short u16;
typedef __attribute__((ext_vector_type(8))) short bf16x8;
typedef __attribute__((ext_vector_type(4))) float f32x4;
typedef __attribute__((ext_vector_type(4))) unsigned int u32x4;

__device__ __forceinline__ float b2f(u16 b){
  unsigned u = ((unsigned)b) << 16; float f; __builtin_memcpy(&f, &u, 4); return f;
}
__device__ __forceinline__ u16 f2b(float f){
  unsigned u; __builtin_memcpy(&u, &f, 4); u += 0x7FFF + ((u >> 16) & 1); return (u16)(u >> 16);
}

// ---------------- preconvert: bf16 copies + transposed weight layouts ----------------
// wt1t[p][n][k], k padded 272->320 with zeros; wt2t[p][n][k]; nw1t[t][n][k]; nw2t[t][n][k]
#define NX   (N_NODES*128)
#define NW1T (4*320*128)
#define NW2T (4*128*128)
#define NN1  (2*256*128)
#define NN2  (2*128*128)
// total = 2560000+163840+65536+65536+32768 = 2887680 = 11280*256

__global__ void k_preconv(const float* __restrict__ x,
                          const float* __restrict__ ew1, const float* __restrict__ ew2,
                          const float* __restrict__ nw1, const float* __restrict__ nw2,
                          u16* __restrict__ x0b,
                          u16* __restrict__ wt1t, u16* __restrict__ wt2t,
                          u16* __restrict__ nw1t, u16* __restrict__ nw2t)
{
  int t = blockIdx.x * 256 + threadIdx.x;
  if (t < NX) { x0b[t] = f2b(x[t]); return; }
  t -= NX;
  if (t < NW1T) {
    int p = t / 40960, r = t % 40960; int k = r >> 7, n = r & 127;
    float v = (k < 272) ? ew1[(p * 272 + k) * 128 + n] : 0.f;
    wt1t[(p * 128 + n) * 320 + k] = f2b(v);
    return;
  }
  t -= NW1T;
  if (t < NW2T) {
    int p = t >> 14, r = t & 16383; int k = r >> 7, n = r & 127;
    wt2t[(p * 128 + n) * 128 + k] = f2b(ew2[(p * 128 + k) * 128 + n]);
    return;
  }
  t -= NW2T;
  if (t < NN1) {
    int ty = t >> 15, r = t & 32767; int k = r >> 7, n = r & 127;
    nw1t[(ty * 128 + n) * 256 + k] = f2b(nw1[(ty * 256 + k) * 128 + n]);
    return;
  }
  t -= NN1;
  if (t < NN2) {
    int ty = t >> 14, r = t & 16383; int k = r >> 7, n = r & 127;
    nw2t[(ty * 128 + n) * 128 + k] = f2b(nw2[(ty * 128 + k) * 128 + n]);
  }
}

// ---------------- counting sort by key = pair*N + row ----------------
__global__ void k_hist(const int* __restrict__ ei, const int* __restrict__ ntp,
                       int* __restrict__ hist, int* __restrict__ hist_nt)
{
  int t = blockIdx.x * 256 + threadIdx.x;
  if (t < N_EDGES) {
    int r = ei[t];
    int c = ei[N_EDGES + t];
    int tr = ntp[r], tc = ntp[c];
    atomicAdd(&hist[(tr * 2 + tc) * N_NODES + r], 1);
  }
  if (t < N_NODES) atomicAdd(&hist_nt[ntp[t]], 1);
}

__global__ void k_scan1(const int* __restrict__ hist, int* __restrict__ parts)
{
  __shared__ int s[256];
  int i = blockIdx.x * 256 + threadIdx.x;
  s[threadIdx.x] = (i < NBINS) ? hist[i] : 0;
  __syncthreads();
  for (int off = 128; off > 0; off >>= 1) {
    if (threadIdx.x < off) s[threadIdx.x] += s[threadIdx.x + off];
    __syncthreads();
  }
  if (threadIdx.x == 0) parts[blockIdx.x] = s[0];
}

__global__ void k_scan2(int* __restrict__ parts)
{
  __shared__ int s[512];
  int t = threadIdx.x;
  int v = (t < SCAN_NBLK) ? parts[t] : 0;
  s[t] = v; __syncthreads();
  for (int off = 1; off < 512; off <<= 1) {
    int xv = (t >= off) ? s[t - off] : 0;
    __syncthreads();
    s[t] += xv;
    __syncthreads();
  }
  if (t < SCAN_NBLK) parts[t] = s[t] - v;
}

__global__ void k_scan3(const int* __restrict__ hist, const int* __restrict__ parts,
                        int* __restrict__ bstart, int* __restrict__ bcur)
{
  __shared__ int s[256];
  int i = blockIdx.x * 256 + threadIdx.x;
  int v = (i < NBINS) ? hist[i] : 0;
  s[threadIdx.x] = v; __syncthreads();
  for (int off = 1; off < 256; off <<= 1) {
    int xv = (threadIdx.x >= off) ? s[threadIdx.x - off] : 0;
    __syncthreads();
    s[threadIdx.x] += xv;
    __syncthreads();
  }
  int excl = s[threadIdx.x] - v + parts[blockIdx.x];
  if (i < NBINS) { bstart[i] = excl; bcur[i] = excl; }
  if (i == 0) bstart[NBINS] = N_EDGES;
}

__global__ void k_scatter(const int* __restrict__ ei, const int* __restrict__ ntp,
                          int* __restrict__ bcur,
                          int* __restrict__ srow, int* __restrict__ scol, int* __restrict__ seid,
                          int* __restrict__ cur_nt, const int* __restrict__ hist_nt,
                          int* __restrict__ nidx)
{
  int t = blockIdx.x * 256 + threadIdx.x;
  if (t < N_EDGES) {
    int r = ei[t], c = ei[N_EDGES + t];
    int tr = ntp[r], tc = ntp[c];
    int key = (tr * 2 + tc) * N_NODES + r;
    int pos = atomicAdd(&bcur[key], 1);
    srow[pos] = r; scol[pos] = c; seid[pos] = t;
  }
  if (t < N_NODES) {
    int ty = ntp[t];
    int pos = atomicAdd(&cur_nt[ty], 1) + (ty ? hist_nt[0] : 0);
    nidx[pos] = t;
  }
}

// ---------------- edge MLP: per-pair batched GEMMs, h2 -> scratch (sorted order) ----------------
// tile: 256 edges x 128 out; 4 waves of 128x64; K1=320 (padded), K2=128
__launch_bounds__(256, 1)
__global__ void k_edge(const u16* __restrict__ x0b, const float* __restrict__ ea,
                       const u16* __restrict__ wt1t, const u16* __restrict__ wt2t,
                       const float* __restrict__ eb1, const float* __restrict__ eb2,
                       const int* __restrict__ bstart,
                       const int* __restrict__ srow, const int* __restrict__ scol,
                       const int* __restrict__ seid,
                       u16* __restrict__ h2s)
{
  __shared__ u16 sEIN[2 * 256 * 72];   // double-buffered 64-k chunks, stride 72 (144B)
  __shared__ u16 sW1[2 * 128 * 72];
  __shared__ u16 sW2[128 * 136];       // full ew2^T, stride 136 (272B)
  __shared__ float sEb1[128];
  __shared__ float sEb2[128];
  __shared__ int sRow[256];
  __shared__ int sCol[256];
  __shared__ int sEid[256];

  const int p    = blockIdx.y;
  const int tid  = threadIdx.x;
  const int lane = tid & 63;
  const int wid  = tid >> 6;
  const int wr   = wid >> 1;   // row half (128 rows each)
  const int wc   = wid & 1;    // col half (64 cols each)
  const int llo  = lane & 15;
  const int lhi  = lane >> 4;

  const int base_p = bstart[p * N_NODES];
  const int end_p  = bstart[(p + 1) * N_NODES];

  for (int i = tid; i < 128 * 128; i += 256) {
    int n = i >> 7, k = i & 127;
    sW2[n * 136 + k] = wt2t[(p * 128 + n) * 128 + k];
  }
  if (tid < 128) { sEb1[tid] = eb1[p * 128 + tid]; sEb2[tid] = eb2[p * 128 + tid]; }

  const u16* wbase = wt1t + (p * 128 + (tid & 127)) * 320 + (tid >> 7) * 32;

  for (int ts = base_p + blockIdx.x * 256; ts < end_p; ts += gridDim.x * 256) {
    const int cnt = min(256, end_p - ts);
    {
      int r = 0, c = 0, e = 0;
      if (tid < cnt) { r = srow[ts + tid]; c = scol[ts + tid]; e = seid[ts + tid]; }
      sRow[tid] = r; sCol[tid] = c; sEid[tid] = e;
    }
    __syncthreads();
    const int myRow = sRow[tid], myCol = sCol[tid], myEid = sEid[tid];

    // prologue: stage chunk 0 (k 0..63 = x0[row][0..63]) + W1 chunk 0
    {
      u32x4 ld[8], lw[4];
      const u16* src = &x0b[myRow * 128];
      #pragma unroll
      for (int j = 0; j < 8; ++j) ld[j] = *(const u32x4*)(src + j * 8);
      #pragma unroll
      for (int j = 0; j < 4; ++j) lw[j] = *(const u32x4*)(wbase + j * 8);
      u16* dE = &sEIN[tid * 72];
      #pragma unroll
      for (int j = 0; j < 8; ++j) *(u32x4*)(dE + j * 8) = ld[j];
      u16* dW = &sW1[(tid & 127) * 72 + (tid >> 7) * 32];
      #pragma unroll
      for (int j = 0; j < 4; ++j) *(u32x4*)(dW + j * 8) = lw[j];
    }
    __syncthreads();

    f32x4 acc[8][4];
    #pragma unroll
    for (int i = 0; i < 8; ++i)
      #pragma unroll
      for (int j = 0; j < 4; ++j)
        acc[i][j] = (f32x4){0.f, 0.f, 0.f, 0.f};

    // layer 1: K = 320 in 5 chunks of 64, double-buffered, issue-early / write-late
    #pragma unroll
    for (int ch = 0; ch < 5; ++ch) {
      const int cur = ch & 1;
      u32x4 ldE[8], ldW[4];
      if (ch < 4) {
        const int cn = ch + 1;
        if (cn < 4) {
          const int node = (cn < 2) ? myRow : myCol;
          const u16* src = &x0b[node * 128 + (cn & 1) * 64];
          #pragma unroll
          for (int j = 0; j < 8; ++j) ldE[j] = *(const u32x4*)(src + j * 8);
        } else {
          // k 256..319: 16 f32 edge_attr -> bf16, rest zero pad
          const float* src = &ea[myEid * 16];
          float v[16];
          #pragma unroll
          for (int j = 0; j < 4; ++j) {
            f32x4 f = *(const f32x4*)(src + j * 4);
            v[j*4+0]=f[0]; v[j*4+1]=f[1]; v[j*4+2]=f[2]; v[j*4+3]=f[3];
          }
          #pragma unroll
          for (int w = 0; w < 4; ++w)
            ldE[0][w] = (unsigned)f2b(v[2*w]) | ((unsigned)f2b(v[2*w+1]) << 16);
          #pragma unroll
          for (int w = 0; w < 4; ++w)
            ldE[1][w] = (unsigned)f2b(v[8+2*w]) | ((unsigned)f2b(v[9+2*w]) << 16);
          #pragma unroll
          for (int j = 2; j < 8; ++j) ldE[j] = (u32x4){0u, 0u, 0u, 0u};
        }
        #pragma unroll
        for (int j = 0; j < 4; ++j) ldW[j] = *(const u32x4*)(wbase + cn * 64 + j * 8);
      }
      #pragma unroll
      for (int ks = 0; ks < 2; ++ks) {
        const int kk = ks * 32 + lhi * 8;
        bf16x8 a[8], b[4];
        #pragma unroll
        for (int i = 0; i < 8; ++i)
          a[i] = *(const bf16x8*)&sEIN[cur * (256 * 72) + (wr * 128 + i * 16 + llo) * 72 + kk];
        #pragma unroll
        for (int j = 0; j < 4; ++j)
          b[j] = *(const bf16x8*)&sW1[cur * (128 * 72) + (wc * 64 + j * 16 + llo) * 72 + kk];
        #pragma unroll
        for (int i = 0; i < 8; ++i)
          #pragma unroll
          for (int j = 0; j < 4; ++j)
            acc[i][j] = __builtin_amdgcn_mfma_f32_16x16x32_bf16(a[i], b[j], acc[i][j], 0, 0, 0);
      }
      if (ch < 4) {
        const int nb = cur ^ 1;
        u16* dE = &sEIN[nb * (256 * 72) + tid * 72];
        #pragma unroll
        for (int j = 0; j < 8; ++j) *(u32x4*)(dE + j * 8) = ldE[j];
        u16* dW = &sW1[nb * (128 * 72) + (tid & 127) * 72 + (tid >> 7) * 32];
        #pragma unroll
        for (int j = 0; j < 4; ++j) *(u32x4*)(dW + j * 8) = ldW[j];
      }
      __syncthreads();
    }

    // h1 = relu(acc + eb1) -> bf16, stored over sEIN (stride 136)
    u16* sH1 = sEIN;
    #pragma unroll
    for (int i = 0; i < 8; ++i) {
      #pragma unroll
      for (int j = 0; j < 4; ++j) {
        const int c = wc * 64 + j * 16 + llo;
        const float bias = sEb1[c];
        #pragma unroll
        for (int r = 0; r < 4; ++r) {
          const int m = wr * 128 + i * 16 + lhi * 4 + r;
          float v = acc[i][j][r] + bias;
          v = v > 0.f ? v : 0.f;
          sH1[m * 136 + c] = f2b(v);
        }
      }
    }
    __syncthreads();

    #pragma unroll
    for (int i = 0; i < 8; ++i)
      #pragma unroll
      for (int j = 0; j < 4; ++j)
        acc[i][j] = (f32x4){0.f, 0.f, 0.f, 0.f};

    // layer 2: K = 128
    #pragma unroll
    for (int ck = 0; ck < 4; ++ck) {
      const int kk = ck * 32 + lhi * 8;
      bf16x8 a[8], b[4];
      #pragma unroll
      for (int i = 0; i < 8; ++i)
        a[i] = *(const bf16x8*)&sH1[(wr * 128 + i * 16 + llo) * 136 + kk];
      #pragma unroll
      for (int j = 0; j < 4; ++j)
        b[j] = *(const bf16x8*)&sW2[(wc * 64 + j * 16 + llo) * 136 + kk];
      #pragma unroll
      for (int i = 0; i < 8; ++i)
        #pragma unroll
        for (int j = 0; j < 4; ++j)
          acc[i][j] = __builtin_amdgcn_mfma_f32_16x16x32_bf16(a[i], b[j], acc[i][j], 0, 0, 0);
    }

    // h2 = relu(acc + eb2) -> bf16 scratch at sorted position
    #pragma unroll
    for (int i = 0; i < 8; ++i) {
      #pragma unroll
      for (int j = 0; j < 4; ++j) {
        const int c = wc * 64 + j * 16 + llo;
        const float bias = sEb2[c];
        #pragma unroll
        for (int r = 0; r < 4; ++r) {
          const int m = wr * 128 + i * 16 + lhi * 4 + r;
          if (m < cnt) {
            float v = acc[i][j][r] + bias;
            v = v > 0.f ? v : 0.f;
            h2s[(ts + m) * 128 + c] = f2b(v);
          }
        }
      }
    }
  }
}

// ---------------- node MLP: type-bucketed, agg = contiguous-run sums (no atomics) ----------------
__launch_bounds__(256, 1)
__global__ void k_node(const u16* __restrict__ x0b, const float* __restrict__ xf,
                       const u16* __restrict__ h2s,
                       const u16* __restrict__ nw1t, const u16* __restrict__ nw2t,
                       const float* __restrict__ nb1, const float* __restrict__ nb2,
                       const int* __restrict__ bstart,
                       const int* __restrict__ nidx, const int* __restrict__ hist_nt,
                       float* __restrict__ out)
{
  const int ty    = blockIdx.y;
  const int cnt0  = hist_nt[0];
  const int cnt_t = ty ? (N_NODES - cnt0) : cnt0;
  const int t0    = blockIdx.x * 64;
  if (t0 >= cnt_t) return;
  const int base_t = ty ? cnt0 : 0;

  __shared__ u16 sNIN[64 * 264];     // node_in, stride 264 (528B)
  __shared__ u16 sNW1[128 * 264];
  __shared__ u16 sNW2[128 * 136];
  __shared__ float sNb1[128];
  __shared__ float sNb2[128];
  __shared__ int sNid[64];

  const int tid  = threadIdx.x;
  const int lane = tid & 63;
  const int wid  = tid >> 6;
  const int llo  = lane & 15;
  const int lhi  = lane >> 4;
  const int cnt  = min(64, cnt_t - t0);

  for (int i = tid; i < 128 * 256; i += 256) {
    int n = i >> 8, k = i & 255;
    sNW1[n * 264 + k] = nw1t[(ty * 128 + n) * 256 + k];
  }
  for (int i = tid; i < 128 * 128; i += 256) {
    int n = i >> 7, k = i & 127;
    sNW2[n * 136 + k] = nw2t[(ty * 128 + n) * 128 + k];
  }
  if (tid < 128) { sNb1[tid] = nb1[ty * 128 + tid]; sNb2[tid] = nb2[ty * 128 + tid]; }
  if (tid < 64) {
    int nid = 0;
    if (tid < cnt) nid = nidx[base_t + t0 + tid];
    sNid[tid] = nid;
  }
  __syncthreads();

  // stage node_in: x part + agg part (sum of two contiguous h2 runs)
  {
    const int m = tid >> 2, q = tid & 3;
    const int nid = sNid[m];
    const u16* xs = &x0b[nid * 128 + q * 32];
    u16* dst = &sNIN[m * 264 + q * 32];
    #pragma unroll
    for (int j = 0; j < 4; ++j) *(u32x4*)(dst + j * 8) = *(const u32x4*)(xs + j * 8);

    float a[32];
    #pragma unroll
    for (int j = 0; j < 32; ++j) a[j] = 0.f;
    #pragma unroll
    for (int pr = 0; pr < 2; ++pr) {
      const int key = (ty * 2 + pr) * N_NODES + nid;
      const int s = bstart[key], e = bstart[key + 1];
      for (int pos = s; pos < e; ++pos) {
        const u16* hp = &h2s[pos * 128 + q * 32];
        #pragma unroll
        for (int j = 0; j < 4; ++j) {
          u32x4 v = *(const u32x4*)(hp + j * 8);
          #pragma unroll
          for (int w = 0; w < 4; ++w) {
            unsigned uu = v[w];
            a[j * 8 + w * 2 + 0] += b2f((u16)(uu & 0xFFFFu));
            a[j * 8 + w * 2 + 1] += b2f((u16)(uu >> 16));
          }
        }
      }
    }
    u16* ad = &sNIN[m * 264 + 128 + q * 32];
    #pragma unroll
    for (int j = 0; j < 32; ++j) ad[j] = f2b(a[j]);
  }
  __syncthreads();

  // layer 1: (64 x 256) @ (256 x 128); wave = 64 rows x 32 cols
  f32x4 acc[4][2];
  #pragma unroll
  for (int i = 0; i < 4; ++i)
    #pragma unroll
    for (int j = 0; j < 2; ++j)
      acc[i][j] = (f32x4){0.f, 0.f, 0.f, 0.f};

  #pragma unroll
  for (int ck = 0; ck < 8; ++ck) {
    const int kk = ck * 32 + lhi * 8;
    bf16x8 a[4], b[2];
    #pragma unroll
    for (int i = 0; i < 4; ++i)
      a[i] = *(const bf16x8*)&sNIN[(i * 16 + llo) * 264 + kk];
    #pragma unroll
    for (int j = 0; j < 2; ++j)
      b[j] = *(const bf16x8*)&sNW1[(wid * 32 + j * 16 + llo) * 264 + kk];
    #pragma unroll
    for (int i = 0; i < 4; ++i)
      #pragma unroll
      for (int j = 0; j < 2; ++j)
        acc[i][j] = __builtin_amdgcn_mfma_f32_16x16x32_bf16(a[i], b[j], acc[i][j], 0, 0, 0);
  }
  __syncthreads();

  u16* sH1 = sNIN;  // reuse (stride 136)
  #pragma unroll
  for (int i = 0; i < 4; ++i) {
    #pragma unroll
    for (int j = 0; j < 2; ++j) {
      const int c = wid * 32 + j * 16 + llo;
      const float bias = sNb1[c];
      #pragma unroll
      for (int r = 0; r < 4; ++r) {
        const int m = i * 16 + lhi * 4 + r;
        float v = acc[i][j][r] + bias;
        v = v > 0.f ? v : 0.f;
        sH1[m * 136 + c] = f2b(v);
      }
    }
  }
  __syncthreads();

  #pragma unroll
  for (int i = 0; i < 4; ++i)
    #pragma unroll
    for (int j = 0; j < 2; ++j)
      acc[i][j] = (f32x4){0.f, 0.f, 0.f, 0.f};

  #pragma unroll
  for (int ck = 0; ck < 4; ++ck) {
    const int kk = ck * 32 + lhi * 8;
    bf16x8 a[4], b[2];
    #pragma unroll
    for (int i = 0; i < 4; ++i)
      a[i] = *(const bf16x8*)&sH1[(i * 16 + llo) * 136 + kk];
    #pragma unroll
    for (int j = 0; j < 2; ++j)
      b[j] = *(const bf16x8*)&sNW2[(wid * 32 + j * 16 + llo) * 136 + kk];
    #pragma unroll
    for (int i = 0; i < 4; ++i)
      #pragma unroll
      for (int j = 0; j < 2; ++j)
        acc[i][j] = __builtin_amdgcn_mfma_f32_16x16x32_bf16(a[i], b[j], acc[i][j], 0, 0, 0);
  }

  // out = n2 + nb2 + x0 residual (f32)
  #pragma unroll
  for (int i = 0; i < 4; ++i) {
    #pragma unroll
    for (int j = 0; j < 2; ++j) {
      const int c = wid * 32 + j * 16 + llo;
      const float bias = sNb2[c];
      #pragma unroll
      for (int r = 0; r < 4; ++r) {
        const int m = i * 16 + lhi * 4 + r;
        if (m < cnt) {
          const int nid = sNid[m];
          out[nid * 128 + c] = acc[i][j][r] + bias + xf[nid * 128 + c];
        }
      }
    }
  }
}

// ---------------- launch ----------------
extern "C" void kernel_launch(void* const* d_in, const int* in_sizes, int n_in,
                              void* d_out, int out_size, void* d_ws, size_t ws_size,
                              hipStream_t stream)
{
  const float* x   = (const float*)d_in[0];
  const int*   ei  = (const int*)d_in[1];     // int64 in reference -> int32 on device
  const float* ea  = (const float*)d_in[2];
  const int*   ntp = (const int*)d_in[3];     // int64 in reference -> int32 on device
  const float* ew1 = (const float*)d_in[4];
  const float* eb1 = (const float*)d_in[5];
  const float* ew2 = (const float*)d_in[6];
  const float* eb2 = (const float*)d_in[7];
  const float* nw1 = (const float*)d_in[8];
  const float* nb1 = (const float*)d_in[9];
  const float* nw2 = (const float*)d_in[10];
  const float* nb2 = (const float*)d_in[11];

  char* ws = (char*)d_ws;
  int* hist    = (int*)(ws + 0);          // 320000 B
  int* hist_nt = (int*)(ws + 320000);     // 8 B
  int* cur_nt  = (int*)(ws + 320008);     // 8 B
  int* parts   = (int*)(ws + 320256);     // 1252 B
  int* bstart  = (int*)(ws + 321792);     // 320004 B
  int* bcur    = (int*)(ws + 642048);     // 320000 B
  int* srow    = (int*)(ws + 962048);     // 1280000 B
  int* scol    = (int*)(ws + 2242048);
  int* seid    = (int*)(ws + 3522048);
  int* nidx    = (int*)(ws + 4802048);    // 80000 B
  u16* x0b     = (u16*)(ws + 4882048);    // 5120000 B
  u16* wt1t    = (u16*)(ws + 10002048);   // 327680 B
  u16* wt2t    = (u16*)(ws + 10329728);   // 131072 B
  u16* nw1t    = (u16*)(ws + 10460800);   // 131072 B
  u16* nw2t    = (u16*)(ws + 10591872);   // 65536 B
  u16* h2s     = (u16*)(ws + 10657408);   // 81920000 B -> total ~92.6 MB

  hipMemsetAsync(ws, 0, 320016, stream);
  k_preconv<<<11280, 256, 0, stream>>>(x, ew1, ew2, nw1, nw2, x0b, wt1t, wt2t, nw1t, nw2t);
  k_hist<<<1250, 256, 0, stream>>>(ei, ntp, hist, hist_nt);
  k_scan1<<<SCAN_NBLK, 256, 0, stream>>>(hist, parts);
  k_scan2<<<1, 512, 0, stream>>>(parts);
  k_scan3<<<SCAN_NBLK, 256, 0, stream>>>(hist, parts, bstart, bcur);
  k_scatter<<<1250, 256, 0, stream>>>(ei, ntp, bcur, srow, scol, seid, cur_nt, hist_nt, nidx);
  k_edge<<<dim3(64, 4), 256, 0, stream>>>(x0b, ea, wt1t, wt2t, eb1, eb2, bstart, srow, scol, seid, h2s);
  k_node<<<dim3(313, 2), 256, 0, stream>>>(x0b, x, h2s, nw1t, nw2t, nb1, nb2, bstart, nidx, hist_nt, (float*)d_out);
}

// Round 3
// 190.475 us; speedup vs baseline: 2.7635x; 2.7635x over previous
//
#include <hip/hip_runtime.h>

#define N_NODES 20000
#define N_EDGES 320000
#define NBINS   (4*N_NODES)
#define SCAN_NBLK 313

typedef unsigned short u16;
typedef __attribute__((ext_vector_type(8))) short bf16x8;
typedef __attribute__((ext_vector_type(4))) float f32x4;
typedef __attribute__((ext_vector_type(4))) unsigned int u32x4;

__device__ __forceinline__ float b2f(u16 b){
  unsigned u = ((unsigned)b) << 16; float f; __builtin_memcpy(&f, &u, 4); return f;
}
__device__ __forceinline__ u16 f2b(float f){
  unsigned u; __builtin_memcpy(&u, &f, 4); u += 0x7FFF + ((u >> 16) & 1); return (u16)(u >> 16);
}

// ---------------- preconvert: bf16 copies + transposed weight layouts ----------------
#define NX   (N_NODES*128)
#define NW1T (4*320*128)
#define NW2T (4*128*128)
#define NN1  (2*256*128)
#define NN2  (2*128*128)

__global__ void k_preconv(const float* __restrict__ x,
                          const float* __restrict__ ew1, const float* __restrict__ ew2,
                          const float* __restrict__ nw1, const float* __restrict__ nw2,
                          u16* __restrict__ x0b,
                          u16* __restrict__ wt1t, u16* __restrict__ wt2t,
                          u16* __restrict__ nw1t, u16* __restrict__ nw2t)
{
  int t = blockIdx.x * 256 + threadIdx.x;
  if (t < NX) { x0b[t] = f2b(x[t]); return; }
  t -= NX;
  if (t < NW1T) {
    int p = t / 40960, r = t % 40960; int k = r >> 7, n = r & 127;
    float v = (k < 272) ? ew1[(p * 272 + k) * 128 + n] : 0.f;
    wt1t[(p * 128 + n) * 320 + k] = f2b(v);
    return;
  }
  t -= NW1T;
  if (t < NW2T) {
    int p = t >> 14, r = t & 16383; int k = r >> 7, n = r & 127;
    wt2t[(p * 128 + n) * 128 + k] = f2b(ew2[(p * 128 + k) * 128 + n]);
    return;
  }
  t -= NW2T;
  if (t < NN1) {
    int ty = t >> 15, r = t & 32767; int k = r >> 7, n = r & 127;
    nw1t[(ty * 128 + n) * 256 + k] = f2b(nw1[(ty * 256 + k) * 128 + n]);
    return;
  }
  t -= NN1;
  if (t < NN2) {
    int ty = t >> 14, r = t & 16383; int k = r >> 7, n = r & 127;
    nw2t[(ty * 128 + n) * 128 + k] = f2b(nw2[(ty * 128 + k) * 128 + n]);
  }
}

// ---------------- pass A: histogram + per-edge rank (atomic return reused) ----------------
__global__ void k_hist(const int* __restrict__ ei, const int* __restrict__ ntp,
                       int* __restrict__ hist, int* __restrict__ hist_nt,
                       u16* __restrict__ srank)
{
  int t = blockIdx.x * 256 + threadIdx.x;
  int lane = threadIdx.x & 63;
  if (t < N_EDGES) {
    int r = ei[t], c = ei[N_EDGES + t];
    int tr = ntp[r], tc = ntp[c];
    int key = (tr * 2 + tc) * N_NODES + r;
    int rk = atomicAdd(&hist[key], 1);
    srank[t] = (u16)rk;
  }
  // node-type counts, wave-aggregated (2 atomics per wave, not 64)
  bool valid = t < N_NODES;
  int ty = valid ? ntp[t] : -1;
  unsigned long long m0 = __ballot(ty == 0);
  unsigned long long m1 = __ballot(ty == 1);
  if (lane == 0) {
    int c0 = __popcll(m0), c1 = __popcll(m1);
    if (c0) atomicAdd(&hist_nt[0], c0);
    if (c1) atomicAdd(&hist_nt[1], c1);
  }
}

__global__ void k_scan1(const int* __restrict__ hist, int* __restrict__ parts)
{
  __shared__ int s[256];
  int i = blockIdx.x * 256 + threadIdx.x;
  s[threadIdx.x] = (i < NBINS) ? hist[i] : 0;
  __syncthreads();
  for (int off = 128; off > 0; off >>= 1) {
    if (threadIdx.x < off) s[threadIdx.x] += s[threadIdx.x + off];
    __syncthreads();
  }
  if (threadIdx.x == 0) parts[blockIdx.x] = s[0];
}

__global__ void k_scan2(int* __restrict__ parts)
{
  __shared__ int s[512];
  int t = threadIdx.x;
  int v = (t < SCAN_NBLK) ? parts[t] : 0;
  s[t] = v; __syncthreads();
  for (int off = 1; off < 512; off <<= 1) {
    int xv = (t >= off) ? s[t - off] : 0;
    __syncthreads();
    s[t] += xv;
    __syncthreads();
  }
  if (t < SCAN_NBLK) parts[t] = s[t] - v;
}

__global__ void k_scan3(const int* __restrict__ hist, const int* __restrict__ parts,
                        int* __restrict__ bstart)
{
  __shared__ int s[256];
  int i = blockIdx.x * 256 + threadIdx.x;
  int v = (i < NBINS) ? hist[i] : 0;
  s[threadIdx.x] = v; __syncthreads();
  for (int off = 1; off < 256; off <<= 1) {
    int xv = (threadIdx.x >= off) ? s[threadIdx.x - off] : 0;
    __syncthreads();
    s[threadIdx.x] += xv;
    __syncthreads();
  }
  int excl = s[threadIdx.x] - v + parts[blockIdx.x];
  if (i < NBINS) bstart[i] = excl;
  if (i == 0) bstart[NBINS] = N_EDGES;
}

// ---------------- pass B: placement (no atomics on the edge path) ----------------
__global__ void k_place(const int* __restrict__ ei, const int* __restrict__ ntp,
                        const u16* __restrict__ srank, const int* __restrict__ bstart,
                        int2* __restrict__ sedge,
                        int* __restrict__ cur_nt, const int* __restrict__ hist_nt,
                        int* __restrict__ nidx)
{
  int t = blockIdx.x * 256 + threadIdx.x;
  int lane = threadIdx.x & 63;
  if (t < N_EDGES) {
    int r = ei[t], c = ei[N_EDGES + t];
    int tr = ntp[r], tc = ntp[c];
    int key = (tr * 2 + tc) * N_NODES + r;
    int pos = bstart[key] + (int)srank[t];
    int2 v; v.x = r | (c << 15); v.y = t;
    sedge[pos] = v;
  }
  // node index grouped by type, wave-aggregated
  bool valid = t < N_NODES;
  int ty = valid ? ntp[t] : -1;
  unsigned long long m0 = __ballot(ty == 0);
  unsigned long long m1 = __ballot(ty == 1);
  int b0 = 0, b1 = 0;
  if (lane == 0) {
    int c0 = __popcll(m0), c1 = __popcll(m1);
    if (c0) b0 = atomicAdd(&cur_nt[0], c0);
    if (c1) b1 = atomicAdd(&cur_nt[1], c1);
  }
  b0 = __shfl(b0, 0); b1 = __shfl(b1, 0);
  if (valid) {
    unsigned long long lt = (1ull << lane) - 1ull;
    int pos = (ty == 0) ? (b0 + __popcll(m0 & lt))
                        : (hist_nt[0] + b1 + __popcll(m1 & lt));
    nidx[pos] = t;
  }
}

// ---------------- edge MLP: 512 threads, 8 waves of 64x64, dbuf K-chunks ----------------
__launch_bounds__(512, 2)
__global__ void k_edge(const u16* __restrict__ x0b, const float* __restrict__ ea,
                       const u16* __restrict__ wt1t, const u16* __restrict__ wt2t,
                       const float* __restrict__ eb1, const float* __restrict__ eb2,
                       const int* __restrict__ bstart, const int2* __restrict__ sedge,
                       u16* __restrict__ h2s)
{
  __shared__ u16 sEIN[2 * 256 * 72];   // double-buffered 64-k chunks, stride 72 (144B)
  __shared__ u16 sW1[2 * 128 * 72];
  __shared__ u16 sW2[128 * 136];       // full ew2^T, stride 136 (272B)
  __shared__ float sEb1[128];
  __shared__ float sEb2[128];
  __shared__ int sRow[256];
  __shared__ int sCol[256];
  __shared__ int sEid[256];

  const int p    = blockIdx.y;
  const int tid  = threadIdx.x;
  const int lane = tid & 63;
  const int wid  = tid >> 6;          // 0..7
  const int wr   = wid >> 1;          // row quarter (64 rows)
  const int wc   = wid & 1;           // col half (64 cols)
  const int llo  = lane & 15;
  const int lhi  = lane >> 4;
  const int rr   = tid >> 1;          // staged edge row 0..255
  const int sub  = tid & 1;           // k-half of 64-chunk
  const int wn   = tid & 127;         // W1 n index
  const int wkq  = (tid >> 7) & 3;    // W1 k-quarter (16 k each)

  const int base_p = bstart[p * N_NODES];
  const int end_p  = bstart[(p + 1) * N_NODES];

  for (int i = tid; i < 128 * 128; i += 512) {
    int n = i >> 7, k = i & 127;
    sW2[n * 136 + k] = wt2t[(p * 128 + n) * 128 + k];
  }
  if (tid < 128) { sEb1[tid] = eb1[p * 128 + tid]; sEb2[tid] = eb2[p * 128 + tid]; }

  const u16* wbase = wt1t + (p * 128 + wn) * 320 + wkq * 16;

  for (int ts = base_p + blockIdx.x * 256; ts < end_p; ts += gridDim.x * 256) {
    const int cnt = min(256, end_p - ts);
    if (tid < 256) {
      int2 v = {0, 0};
      if (tid < cnt) v = sedge[ts + tid];
      sRow[tid] = v.x & 32767; sCol[tid] = v.x >> 15; sEid[tid] = v.y;
    }
    __syncthreads();
    const int myRow = sRow[rr], myCol = sCol[rr], myEid = sEid[rr];

    // prologue: stage chunk 0 (k 0..63 = x0[row][0..63]) + W1 chunk 0
    {
      u32x4 ld[4], lw[2];
      const u16* src = &x0b[myRow * 128 + sub * 32];
      #pragma unroll
      for (int j = 0; j < 4; ++j) ld[j] = *(const u32x4*)(src + j * 8);
      #pragma unroll
      for (int j = 0; j < 2; ++j) lw[j] = *(const u32x4*)(wbase + j * 8);
      u16* dE = &sEIN[rr * 72 + sub * 32];
      #pragma unroll
      for (int j = 0; j < 4; ++j) *(u32x4*)(dE + j * 8) = ld[j];
      u16* dW = &sW1[wn * 72 + wkq * 16];
      #pragma unroll
      for (int j = 0; j < 2; ++j) *(u32x4*)(dW + j * 8) = lw[j];
    }
    __syncthreads();

    f32x4 acc[4][4];
    #pragma unroll
    for (int i = 0; i < 4; ++i)
      #pragma unroll
      for (int j = 0; j < 4; ++j)
        acc[i][j] = (f32x4){0.f, 0.f, 0.f, 0.f};

    // layer 1: K = 320 in 5 chunks of 64, double-buffered, issue-early / write-late
    #pragma unroll
    for (int ch = 0; ch < 5; ++ch) {
      const int cur = ch & 1;
      u32x4 ldE[4], ldW[2];
      if (ch < 4) {
        const int cn = ch + 1;
        if (cn < 4) {
          const int node = (cn < 2) ? myRow : myCol;
          const u16* src = &x0b[node * 128 + (cn & 1) * 64 + sub * 32];
          #pragma unroll
          for (int j = 0; j < 4; ++j) ldE[j] = *(const u32x4*)(src + j * 8);
        } else {
          // k 256..319: 16 f32 edge_attr -> bf16 (sub 0, first 16), rest zero
          #pragma unroll
          for (int j = 0; j < 4; ++j) ldE[j] = (u32x4){0u, 0u, 0u, 0u};
          if (sub == 0) {
            const float* src = &ea[myEid * 16];
            float v[16];
            #pragma unroll
            for (int j = 0; j < 4; ++j) {
              f32x4 f = *(const f32x4*)(src + j * 4);
              v[j*4+0]=f[0]; v[j*4+1]=f[1]; v[j*4+2]=f[2]; v[j*4+3]=f[3];
            }
            #pragma unroll
            for (int w = 0; w < 4; ++w)
              ldE[0][w] = (unsigned)f2b(v[2*w]) | ((unsigned)f2b(v[2*w+1]) << 16);
            #pragma unroll
            for (int w = 0; w < 4; ++w)
              ldE[1][w] = (unsigned)f2b(v[8+2*w]) | ((unsigned)f2b(v[9+2*w]) << 16);
          }
        }
        #pragma unroll
        for (int j = 0; j < 2; ++j) ldW[j] = *(const u32x4*)(wbase + cn * 64 + j * 8);
      }
      #pragma unroll
      for (int ks = 0; ks < 2; ++ks) {
        const int kk = ks * 32 + lhi * 8;
        bf16x8 a[4], b[4];
        #pragma unroll
        for (int i = 0; i < 4; ++i)
          a[i] = *(const bf16x8*)&sEIN[cur * (256 * 72) + (wr * 64 + i * 16 + llo) * 72 + kk];
        #pragma unroll
        for (int j = 0; j < 4; ++j)
          b[j] = *(const bf16x8*)&sW1[cur * (128 * 72) + (wc * 64 + j * 16 + llo) * 72 + kk];
        #pragma unroll
        for (int i = 0; i < 4; ++i)
          #pragma unroll
          for (int j = 0; j < 4; ++j)
            acc[i][j] = __builtin_amdgcn_mfma_f32_16x16x32_bf16(a[i], b[j], acc[i][j], 0, 0, 0);
      }
      if (ch < 4) {
        const int nb = cur ^ 1;
        u16* dE = &sEIN[nb * (256 * 72) + rr * 72 + sub * 32];
        #pragma unroll
        for (int j = 0; j < 4; ++j) *(u32x4*)(dE + j * 8) = ldE[j];
        u16* dW = &sW1[nb * (128 * 72) + wn * 72 + wkq * 16];
        #pragma unroll
        for (int j = 0; j < 2; ++j) *(u32x4*)(dW + j * 8) = ldW[j];
      }
      __syncthreads();
    }

    // h1 = relu(acc + eb1) -> bf16, stored over sEIN (stride 136)
    u16* sH1 = sEIN;
    #pragma unroll
    for (int i = 0; i < 4; ++i) {
      #pragma unroll
      for (int j = 0; j < 4; ++j) {
        const int c = wc * 64 + j * 16 + llo;
        const float bias = sEb1[c];
        #pragma unroll
        for (int r = 0; r < 4; ++r) {
          const int m = wr * 64 + i * 16 + lhi * 4 + r;
          float v = acc[i][j][r] + bias;
          v = v > 0.f ? v : 0.f;
          sH1[m * 136 + c] = f2b(v);
        }
      }
    }
    __syncthreads();

    #pragma unroll
    for (int i = 0; i < 4; ++i)
      #pragma unroll
      for (int j = 0; j < 4; ++j)
        acc[i][j] = (f32x4){0.f, 0.f, 0.f, 0.f};

    // layer 2: K = 128
    #pragma unroll
    for (int ck = 0; ck < 4; ++ck) {
      const int kk = ck * 32 + lhi * 8;
      bf16x8 a[4], b[4];
      #pragma unroll
      for (int i = 0; i < 4; ++i)
        a[i] = *(const bf16x8*)&sH1[(wr * 64 + i * 16 + llo) * 136 + kk];
      #pragma unroll
      for (int j = 0; j < 4; ++j)
        b[j] = *(const bf16x8*)&sW2[(wc * 64 + j * 16 + llo) * 136 + kk];
      #pragma unroll
      for (int i = 0; i < 4; ++i)
        #pragma unroll
        for (int j = 0; j < 4; ++j)
          acc[i][j] = __builtin_amdgcn_mfma_f32_16x16x32_bf16(a[i], b[j], acc[i][j], 0, 0, 0);
    }

    // h2 = relu(acc + eb2) -> bf16 scratch at sorted position
    #pragma unroll
    for (int i = 0; i < 4; ++i) {
      #pragma unroll
      for (int j = 0; j < 4; ++j) {
        const int c = wc * 64 + j * 16 + llo;
        const float bias = sEb2[c];
        #pragma unroll
        for (int r = 0; r < 4; ++r) {
          const int m = wr * 64 + i * 16 + lhi * 4 + r;
          if (m < cnt) {
            float v = acc[i][j][r] + bias;
            v = v > 0.f ? v : 0.f;
            h2s[(ts + m) * 128 + c] = f2b(v);
          }
        }
      }
    }
    __syncthreads();
  }
}

// ---------------- node MLP: 512 threads, 8 waves, run-sum aggregation ----------------
__launch_bounds__(512, 2)
__global__ void k_node(const u16* __restrict__ x0b, const float* __restrict__ xf,
                       const u16* __restrict__ h2s,
                       const u16* __restrict__ nw1t, const u16* __restrict__ nw2t,
                       const float* __restrict__ nb1, const float* __restrict__ nb2,
                       const int* __restrict__ bstart,
                       const int* __restrict__ nidx, const int* __restrict__ hist_nt,
                       float* __restrict__ out)
{
  const int ty    = blockIdx.y;
  const int cnt0  = hist_nt[0];
  const int cnt_t = ty ? (N_NODES - cnt0) : cnt0;
  const int t0    = blockIdx.x * 64;
  if (t0 >= cnt_t) return;
  const int base_t = ty ? cnt0 : 0;

  __shared__ u16 sNIN[64 * 264];     // node_in, stride 264 (528B)
  __shared__ u16 sNW1[128 * 264];
  __shared__ u16 sNW2[128 * 136];
  __shared__ float sNb1[128];
  __shared__ float sNb2[128];
  __shared__ int sNid[64];

  const int tid  = threadIdx.x;
  const int lane = tid & 63;
  const int wid  = tid >> 6;      // 0..7 -> 16 output cols each
  const int llo  = lane & 15;
  const int lhi  = lane >> 4;
  const int cnt  = min(64, cnt_t - t0);

  for (int i = tid; i < 128 * 256; i += 512) {
    int n = i >> 8, k = i & 255;
    sNW1[n * 264 + k] = nw1t[(ty * 128 + n) * 256 + k];
  }
  for (int i = tid; i < 128 * 128; i += 512) {
    int n = i >> 7, k = i & 127;
    sNW2[n * 136 + k] = nw2t[(ty * 128 + n) * 128 + k];
  }
  if (tid < 128) { sNb1[tid] = nb1[ty * 128 + tid]; sNb2[tid] = nb2[ty * 128 + tid]; }
  if (tid < 64) {
    int nid = 0;
    if (tid < cnt) nid = nidx[base_t + t0 + tid];
    sNid[tid] = nid;
  }
  __syncthreads();

  // stage node_in: x part + agg part (sum of two contiguous h2 runs); 8 threads/node
  {
    const int m = tid >> 3, q = tid & 7;      // 16 channels per thread
    const int nid = sNid[m];
    const u16* xs = &x0b[nid * 128 + q * 16];
    u16* dst = &sNIN[m * 264 + q * 16];
    #pragma unroll
    for (int j = 0; j < 2; ++j) *(u32x4*)(dst + j * 8) = *(const u32x4*)(xs + j * 8);

    float a[16];
    #pragma unroll
    for (int j = 0; j < 16; ++j) a[j] = 0.f;
    #pragma unroll
    for (int pr = 0; pr < 2; ++pr) {
      const int key = (ty * 2 + pr) * N_NODES + nid;
      const int s = bstart[key], e = bstart[key + 1];
      for (int pos = s; pos < e; ++pos) {
        const u16* hp = &h2s[pos * 128 + q * 16];
        #pragma unroll
        for (int j = 0; j < 2; ++j) {
          u32x4 v = *(const u32x4*)(hp + j * 8);
          #pragma unroll
          for (int w = 0; w < 4; ++w) {
            unsigned uu = v[w];
            a[j * 8 + w * 2 + 0] += b2f((u16)(uu & 0xFFFFu));
            a[j * 8 + w * 2 + 1] += b2f((u16)(uu >> 16));
          }
        }
      }
    }
    u16* ad = &sNIN[m * 264 + 128 + q * 16];
    #pragma unroll
    for (int j = 0; j < 16; ++j) ad[j] = f2b(a[j]);
  }
  __syncthreads();

  // layer 1: (64 x 256) @ (256 x 128); wave = 64 rows x 16 cols
  f32x4 acc[4];
  #pragma unroll
  for (int i = 0; i < 4; ++i) acc[i] = (f32x4){0.f, 0.f, 0.f, 0.f};

  #pragma unroll
  for (int ck = 0; ck < 8; ++ck) {
    const int kk = ck * 32 + lhi * 8;
    bf16x8 a[4], b;
    #pragma unroll
    for (int i = 0; i < 4; ++i)
      a[i] = *(const bf16x8*)&sNIN[(i * 16 + llo) * 264 + kk];
    b = *(const bf16x8*)&sNW1[(wid * 16 + llo) * 264 + kk];
    #pragma unroll
    for (int i = 0; i < 4; ++i)
      acc[i] = __builtin_amdgcn_mfma_f32_16x16x32_bf16(a[i], b, acc[i], 0, 0, 0);
  }
  __syncthreads();

  u16* sH1 = sNIN;  // reuse (stride 136)
  #pragma unroll
  for (int i = 0; i < 4; ++i) {
    const int c = wid * 16 + llo;
    const float bias = sNb1[c];
    #pragma unroll
    for (int r = 0; r < 4; ++r) {
      const int m = i * 16 + lhi * 4 + r;
      float v = acc[i][r] + bias;
      v = v > 0.f ? v : 0.f;
      sH1[m * 136 + c] = f2b(v);
    }
  }
  __syncthreads();

  #pragma unroll
  for (int i = 0; i < 4; ++i) acc[i] = (f32x4){0.f, 0.f, 0.f, 0.f};

  #pragma unroll
  for (int ck = 0; ck < 4; ++ck) {
    const int kk = ck * 32 + lhi * 8;
    bf16x8 a[4], b;
    #pragma unroll
    for (int i = 0; i < 4; ++i)
      a[i] = *(const bf16x8*)&sH1[(i * 16 + llo) * 136 + kk];
    b = *(const bf16x8*)&sNW2[(wid * 16 + llo) * 136 + kk];
    #pragma unroll
    for (int i = 0; i < 4; ++i)
      acc[i] = __builtin_amdgcn_mfma_f32_16x16x32_bf16(a[i], b, acc[i], 0, 0, 0);
  }

  // out = n2 + nb2 + x0 residual (f32)
  #pragma unroll
  for (int i = 0; i < 4; ++i) {
    const int c = wid * 16 + llo;
    const float bias = sNb2[c];
    #pragma unroll
    for (int r = 0; r < 4; ++r) {
      const int m = i * 16 + lhi * 4 + r;
      if (m < cnt) {
        const int nid = sNid[m];
        out[nid * 128 + c] = acc[i][r] + bias + xf[nid * 128 + c];
      }
    }
  }
}

// ---------------- launch ----------------
extern "C" void kernel_launch(void* const* d_in, const int* in_sizes, int n_in,
                              void* d_out, int out_size, void* d_ws, size_t ws_size,
                              hipStream_t stream)
{
  const float* x   = (const float*)d_in[0];
  const int*   ei  = (const int*)d_in[1];     // int64 in reference -> int32 on device
  const float* ea  = (const float*)d_in[2];
  const int*   ntp = (const int*)d_in[3];
  const float* ew1 = (const float*)d_in[4];
  const float* eb1 = (const float*)d_in[5];
  const float* ew2 = (const float*)d_in[6];
  const float* eb2 = (const float*)d_in[7];
  const float* nw1 = (const float*)d_in[8];
  const float* nb1 = (const float*)d_in[9];
  const float* nw2 = (const float*)d_in[10];
  const float* nb2 = (const float*)d_in[11];

  char* ws = (char*)d_ws;
  int*  hist    = (int*)(ws + 0);          // 320000 B
  int*  hist_nt = (int*)(ws + 320000);     // 8 B
  int*  cur_nt  = (int*)(ws + 320008);     // 8 B
  int*  parts   = (int*)(ws + 320256);     // 1252 B
  int*  bstart  = (int*)(ws + 321792);     // 320004 B (ends 641796)
  u16*  srank   = (u16*)(ws + 641824);     // 640000 B
  int2* sedge   = (int2*)(ws + 1281824);   // 2560000 B
  int*  nidx    = (int*)(ws + 3841824);    // 80000 B
  u16*  x0b     = (u16*)(ws + 3921824);    // 5120000 B
  u16*  wt1t    = (u16*)(ws + 9041824);    // 327680 B
  u16*  wt2t    = (u16*)(ws + 9369504);    // 131072 B
  u16*  nw1t    = (u16*)(ws + 9500576);    // 131072 B
  u16*  nw2t    = (u16*)(ws + 9631648);    // 65536 B
  u16*  h2s     = (u16*)(ws + 9697184);    // 81920000 B -> total ~91.6 MB

  hipMemsetAsync(ws, 0, 320016, stream);
  k_preconv<<<11280, 256, 0, stream>>>(x, ew1, ew2, nw1, nw2, x0b, wt1t, wt2t, nw1t, nw2t);
  k_hist<<<1250, 256, 0, stream>>>(ei, ntp, hist, hist_nt, srank);
  k_scan1<<<SCAN_NBLK, 256, 0, stream>>>(hist, parts);
  k_scan2<<<1, 512, 0, stream>>>(parts);
  k_scan3<<<SCAN_NBLK, 256, 0, stream>>>(hist, parts, bstart);
  k_place<<<1250, 256, 0, stream>>>(ei, ntp, srank, bstart, sedge, cur_nt, hist_nt, nidx);
  k_edge<<<dim3(64, 4), 512, 0, stream>>>(x0b, ea, wt1t, wt2t, eb1, eb2, bstart, sedge, h2s);
  k_node<<<dim3(313, 2), 512, 0, stream>>>(x0b, x, h2s, nw1t, nw2t, nb1, nb2, bstart, nidx, hist_nt, (float*)d_out);
}

// Round 5
// 188.043 us; speedup vs baseline: 2.7992x; 1.0129x over previous
//
#include <hip/hip_runtime.h>

#define N_NODES 20000
#define N_EDGES 320000
#define NBINS   (4*N_NODES)
#define SCAN_NBLK 313

typedef unsigned short u16;
typedef __attribute__((ext_vector_type(8))) short bf16x8;
typedef __attribute__((ext_vector_type(4))) float f32x4;
typedef __attribute__((ext_vector_type(4))) unsigned int u32x4;
typedef __attribute__((ext_vector_type(2))) unsigned int u32x2;

__device__ __forceinline__ float b2f(u16 b){
  unsigned u = ((unsigned)b) << 16; float f; __builtin_memcpy(&f, &u, 4); return f;
}
__device__ __forceinline__ u16 f2b(float f){
  unsigned u; __builtin_memcpy(&u, &f, 4); u += 0x7FFF + ((u >> 16) & 1); return (u16)(u >> 16);
}
// pack 2 f32 -> 2 bf16 in one u32 (RNE, same as f2b)
__device__ __forceinline__ unsigned cvtpk(float a, float b){
  unsigned r;
  asm("v_cvt_pk_bf16_f32 %0, %1, %2" : "=v"(r) : "v"(a), "v"(b));
  return r;
}

// ---------------- preconvert: bf16 copies + transposed weight layouts ----------------
// wt1t[p][n][288] (k padded 272->288 zeros); wt2t[p][n][128]; nw1t[t][n][256]; nw2t[t][n][128]
#define NX   (N_NODES*128)
#define NW1T (4*288*128)
#define NW2T (4*128*128)
#define NN1  (2*256*128)
#define NN2  (2*128*128)
// total = 2560000+147456+65536+65536+32768 = 2871296 = 11216*256

__global__ void k_preconv(const float* __restrict__ x,
                          const float* __restrict__ ew1, const float* __restrict__ ew2,
                          const float* __restrict__ nw1, const float* __restrict__ nw2,
                          u16* __restrict__ x0b,
                          u16* __restrict__ wt1t, u16* __restrict__ wt2t,
                          u16* __restrict__ nw1t, u16* __restrict__ nw2t)
{
  int t = blockIdx.x * 256 + threadIdx.x;
  if (t < NX) { x0b[t] = f2b(x[t]); return; }
  t -= NX;
  if (t < NW1T) {
    int p = t / 36864, r = t % 36864; int k = r >> 7, n = r & 127;
    float v = (k < 272) ? ew1[(p * 272 + k) * 128 + n] : 0.f;
    wt1t[(p * 128 + n) * 288 + k] = f2b(v);
    return;
  }
  t -= NW1T;
  if (t < NW2T) {
    int p = t >> 14, r = t & 16383; int k = r >> 7, n = r & 127;
    wt2t[(p * 128 + n) * 128 + k] = f2b(ew2[(p * 128 + k) * 128 + n]);
    return;
  }
  t -= NW2T;
  if (t < NN1) {
    int ty = t >> 15, r = t & 32767; int k = r >> 7, n = r & 127;
    nw1t[(ty * 128 + n) * 256 + k] = f2b(nw1[(ty * 256 + k) * 128 + n]);
    return;
  }
  t -= NN1;
  if (t < NN2) {
    int ty = t >> 14, r = t & 16383; int k = r >> 7, n = r & 127;
    nw2t[(ty * 128 + n) * 128 + k] = f2b(nw2[(ty * 128 + k) * 128 + n]);
  }
}

// ---------------- pass A: histogram + per-edge rank ----------------
__global__ void k_hist(const int* __restrict__ ei, const int* __restrict__ ntp,
                       int* __restrict__ hist, int* __restrict__ hist_nt,
                       u16* __restrict__ srank)
{
  int t = blockIdx.x * 256 + threadIdx.x;
  int lane = threadIdx.x & 63;
  if (t < N_EDGES) {
    int r = ei[t], c = ei[N_EDGES + t];
    int tr = ntp[r], tc = ntp[c];
    int key = (tr * 2 + tc) * N_NODES + r;
    int rk = atomicAdd(&hist[key], 1);
    srank[t] = (u16)rk;
  }
  bool valid = t < N_NODES;
  int ty = valid ? ntp[t] : -1;
  unsigned long long m0 = __ballot(ty == 0);
  unsigned long long m1 = __ballot(ty == 1);
  if (lane == 0) {
    int c0 = __popcll(m0), c1 = __popcll(m1);
    if (c0) atomicAdd(&hist_nt[0], c0);
    if (c1) atomicAdd(&hist_nt[1], c1);
  }
}

__global__ void k_scan1(const int* __restrict__ hist, int* __restrict__ parts)
{
  __shared__ int s[256];
  int i = blockIdx.x * 256 + threadIdx.x;
  s[threadIdx.x] = (i < NBINS) ? hist[i] : 0;
  __syncthreads();
  for (int off = 128; off > 0; off >>= 1) {
    if (threadIdx.x < off) s[threadIdx.x] += s[threadIdx.x + off];
    __syncthreads();
  }
  if (threadIdx.x == 0) parts[blockIdx.x] = s[0];
}

__global__ void k_scan2(int* __restrict__ parts)
{
  __shared__ int s[512];
  int t = threadIdx.x;
  int v = (t < SCAN_NBLK) ? parts[t] : 0;
  s[t] = v; __syncthreads();
  for (int off = 1; off < 512; off <<= 1) {
    int xv = (t >= off) ? s[t - off] : 0;
    __syncthreads();
    s[t] += xv;
    __syncthreads();
  }
  if (t < SCAN_NBLK) parts[t] = s[t] - v;
}

__global__ void k_scan3(const int* __restrict__ hist, const int* __restrict__ parts,
                        int* __restrict__ bstart)
{
  __shared__ int s[256];
  int i = blockIdx.x * 256 + threadIdx.x;
  int v = (i < NBINS) ? hist[i] : 0;
  s[threadIdx.x] = v; __syncthreads();
  for (int off = 1; off < 256; off <<= 1) {
    int xv = (threadIdx.x >= off) ? s[threadIdx.x - off] : 0;
    __syncthreads();
    s[threadIdx.x] += xv;
    __syncthreads();
  }
  int excl = s[threadIdx.x] - v + parts[blockIdx.x];
  if (i < NBINS) bstart[i] = excl;
  if (i == 0) bstart[NBINS] = N_EDGES;
}

// ---------------- pass B: placement ----------------
__global__ void k_place(const int* __restrict__ ei, const int* __restrict__ ntp,
                        const u16* __restrict__ srank, const int* __restrict__ bstart,
                        int2* __restrict__ sedge,
                        int* __restrict__ cur_nt, const int* __restrict__ hist_nt,
                        int* __restrict__ nidx)
{
  int t = blockIdx.x * 256 + threadIdx.x;
  int lane = threadIdx.x & 63;
  if (t < N_EDGES) {
    int r = ei[t], c = ei[N_EDGES + t];
    int tr = ntp[r], tc = ntp[c];
    int key = (tr * 2 + tc) * N_NODES + r;
    int pos = bstart[key] + (int)srank[t];
    int2 v; v.x = r | (c << 15); v.y = t;
    sedge[pos] = v;
  }
  bool valid = t < N_NODES;
  int ty = valid ? ntp[t] : -1;
  unsigned long long m0 = __ballot(ty == 0);
  unsigned long long m1 = __ballot(ty == 1);
  int b0 = 0, b1 = 0;
  if (lane == 0) {
    int c0 = __popcll(m0), c1 = __popcll(m1);
    if (c0) b0 = atomicAdd(&cur_nt[0], c0);
    if (c1) b1 = atomicAdd(&cur_nt[1], c1);
  }
  b0 = __shfl(b0, 0); b1 = __shfl(b1, 0);
  if (valid) {
    unsigned long long lt = (1ull << lane) - 1ull;
    int pos = (ty == 0) ? (b0 + __popcll(m0 & lt))
                        : (hist_nt[0] + b1 + __popcll(m1 & lt));
    nidx[pos] = t;
  }
}

// ---------------- edge MLP v3: W1 LDS-resident, flipped MFMA (A=W, B=edges) ----------------
// tile = 128 edges x 128 ch; 8 waves = 2 ch-halves x 4 edge-quarters (64ch x 32e each)
__launch_bounds__(512, 1)
__global__ void k_edge(const u16* __restrict__ x0b, const float* __restrict__ ea,
                       const u16* __restrict__ wt1t, const u16* __restrict__ wt2t,
                       const float* __restrict__ eb1, const float* __restrict__ eb2,
                       const int* __restrict__ bstart, const int2* __restrict__ sedge,
                       u16* __restrict__ h2s)
{
  __shared__ u16 sW1[128 * 296];        // W1^T resident, stride 296 (592B)
  __shared__ u16 sEIN[2 * 128 * 72];    // dbuf 64-k chunks, stride 72; aliased as h1[128][136]
  __shared__ u16 sEA[128 * 40];         // k=256..287 (ea | zeros), stride 40
  __shared__ float sEb1[128];
  __shared__ float sEb2[128];
  __shared__ int2 sMeta[128];

  const int p    = blockIdx.y;
  const int tid  = threadIdx.x;
  const int lane = tid & 63;
  const int wid  = tid >> 6;        // 0..7
  const int wc   = wid & 1;         // ch half (64 ch)
  const int we   = wid >> 1;        // edge quarter (32 edges)
  const int llo  = lane & 15;
  const int lhi  = lane >> 4;
  const int eidx = tid >> 2;        // staging edge 0..127
  const int q    = tid & 3;         // staging k-quarter (16 u16)

  const int base_p = bstart[p * N_NODES];
  const int end_p  = bstart[(p + 1) * N_NODES];

  // stage W1 once per block (128 rows x 288 u16 = 36 chunks of 8 u16 per row)
  for (int i = tid; i < 128 * 36; i += 512) {
    int n = i / 36, c = i % 36;
    *(u32x4*)&sW1[n * 296 + c * 8] = *(const u32x4*)&wt1t[(p * 128 + n) * 288 + c * 8];
  }
  if (tid < 128) { sEb1[tid] = eb1[p * 128 + tid]; sEb2[tid] = eb2[p * 128 + tid]; }

  // W2 fragments into registers (A operand of layer 2)
  bf16x8 w2[4][4];
  #pragma unroll
  for (int i = 0; i < 4; ++i)
    #pragma unroll
    for (int ck = 0; ck < 4; ++ck)
      w2[i][ck] = *(const bf16x8*)&wt2t[(p * 128 + wc * 64 + i * 16 + llo) * 128 + ck * 32 + lhi * 8];

  u16* sH1 = sEIN;   // [128][136] alias

  for (int ts = base_p + blockIdx.x * 128; ts < end_p; ts += 64 * 128) {
    const int cnt = min(128, end_p - ts);
    if (tid < 128) {
      int2 v = {0, 0};
      if (tid < cnt) v = sedge[ts + tid];
      sMeta[tid] = v;
    }
    __syncthreads();
    const int2 me = sMeta[eidx];
    const int myRow = me.x & 32767, myCol = me.x >> 15, myEid = me.y;

    // stage chunk0 (k 0..63 of x0[row]) and sEA (k 256..287)
    {
      const u16* src = &x0b[myRow * 128 + q * 16];
      u32x4 l0 = *(const u32x4*)src;
      u32x4 l1 = *(const u32x4*)(src + 8);
      u16* d = &sEIN[eidx * 72 + q * 16];
      *(u32x4*)d = l0; *(u32x4*)(d + 8) = l1;
      u32x4 pk = (u32x4){0u, 0u, 0u, 0u};
      if (q < 2) {
        f32x4 f0 = *(const f32x4*)&ea[myEid * 16 + q * 8];
        f32x4 f1 = *(const f32x4*)&ea[myEid * 16 + q * 8 + 4];
        pk[0] = cvtpk(f0[0], f0[1]); pk[1] = cvtpk(f0[2], f0[3]);
        pk[2] = cvtpk(f1[0], f1[1]); pk[3] = cvtpk(f1[2], f1[3]);
      }
      *(u32x4*)&sEA[eidx * 40 + q * 8] = pk;
    }
    __syncthreads();

    f32x4 acc[4][2];
    #pragma unroll
    for (int i = 0; i < 4; ++i)
      #pragma unroll
      for (int j = 0; j < 2; ++j)
        acc[i][j] = (f32x4){0.f, 0.f, 0.f, 0.f};

    // layer 1 main: k 0..255 in 4 chunks of 64, dbuf issue-early/write-late
    #pragma unroll
    for (int ch = 0; ch < 4; ++ch) {
      const int cur = ch & 1;
      u32x4 n0, n1;
      const int cn = ch + 1;
      if (cn < 4) {
        const int node = (cn < 2) ? myRow : myCol;
        const u16* src = &x0b[node * 128 + (cn & 1) * 64 + q * 16];
        n0 = *(const u32x4*)src; n1 = *(const u32x4*)(src + 8);
      }
      #pragma unroll
      for (int ks = 0; ks < 2; ++ks) {
        const int kk = ks * 32 + lhi * 8;
        bf16x8 a[4], b[2];
        #pragma unroll
        for (int i = 0; i < 4; ++i)
          a[i] = *(const bf16x8*)&sW1[(wc * 64 + i * 16 + llo) * 296 + ch * 64 + kk];
        #pragma unroll
        for (int j = 0; j < 2; ++j)
          b[j] = *(const bf16x8*)&sEIN[cur * (128 * 72) + (we * 32 + j * 16 + llo) * 72 + kk];
        #pragma unroll
        for (int i = 0; i < 4; ++i)
          #pragma unroll
          for (int j = 0; j < 2; ++j)
            acc[i][j] = __builtin_amdgcn_mfma_f32_16x16x32_bf16(a[i], b[j], acc[i][j], 0, 0, 0);
      }
      if (cn < 4) {
        u16* d = &sEIN[(cur ^ 1) * (128 * 72) + eidx * 72 + q * 16];
        *(u32x4*)d = n0; *(u32x4*)(d + 8) = n1;
      }
      __syncthreads();
    }
    // final K=32 step: k 256..287 (ea real 256..271, zeros beyond)
    {
      const int kk = lhi * 8;
      bf16x8 a[4], b[2];
      #pragma unroll
      for (int i = 0; i < 4; ++i)
        a[i] = *(const bf16x8*)&sW1[(wc * 64 + i * 16 + llo) * 296 + 256 + kk];
      #pragma unroll
      for (int j = 0; j < 2; ++j)
        b[j] = *(const bf16x8*)&sEA[(we * 32 + j * 16 + llo) * 40 + kk];
      #pragma unroll
      for (int i = 0; i < 4; ++i)
        #pragma unroll
        for (int j = 0; j < 2; ++j)
          acc[i][j] = __builtin_amdgcn_mfma_f32_16x16x32_bf16(a[i], b[j], acc[i][j], 0, 0, 0);
    }

    // h1 = relu(acc + eb1) -> packed bf16 LDS [edge][136]
    #pragma unroll
    for (int i = 0; i < 4; ++i) {
      const int chb = wc * 64 + i * 16 + lhi * 4;
      const f32x4 bb = *(const f32x4*)&sEb1[chb];
      #pragma unroll
      for (int j = 0; j < 2; ++j) {
        const int edge = we * 32 + j * 16 + llo;
        float v0 = acc[i][j][0] + bb[0]; v0 = v0 > 0.f ? v0 : 0.f;
        float v1 = acc[i][j][1] + bb[1]; v1 = v1 > 0.f ? v1 : 0.f;
        float v2 = acc[i][j][2] + bb[2]; v2 = v2 > 0.f ? v2 : 0.f;
        float v3 = acc[i][j][3] + bb[3]; v3 = v3 > 0.f ? v3 : 0.f;
        u32x2 pk; pk[0] = cvtpk(v0, v1); pk[1] = cvtpk(v2, v3);
        *(u32x2*)&sH1[edge * 136 + chb] = pk;
      }
    }
    __syncthreads();

    // layer 2: preload B frags (h1), A = w2 regs
    bf16x8 bh[2][4];
    #pragma unroll
    for (int j = 0; j < 2; ++j)
      #pragma unroll
      for (int ck = 0; ck < 4; ++ck)
        bh[j][ck] = *(const bf16x8*)&sH1[(we * 32 + j * 16 + llo) * 136 + ck * 32 + lhi * 8];

    #pragma unroll
    for (int i = 0; i < 4; ++i)
      #pragma unroll
      for (int j = 0; j < 2; ++j)
        acc[i][j] = (f32x4){0.f, 0.f, 0.f, 0.f};
    #pragma unroll
    for (int ck = 0; ck < 4; ++ck)
      #pragma unroll
      for (int i = 0; i < 4; ++i)
        #pragma unroll
        for (int j = 0; j < 2; ++j)
          acc[i][j] = __builtin_amdgcn_mfma_f32_16x16x32_bf16(w2[i][ck], bh[j][ck], acc[i][j], 0, 0, 0);

    // h2 = relu(acc + eb2) -> packed 8B global stores
    #pragma unroll
    for (int i = 0; i < 4; ++i) {
      const int chb = wc * 64 + i * 16 + lhi * 4;
      const f32x4 bb = *(const f32x4*)&sEb2[chb];
      #pragma unroll
      for (int j = 0; j < 2; ++j) {
        const int edge = we * 32 + j * 16 + llo;
        float v0 = acc[i][j][0] + bb[0]; v0 = v0 > 0.f ? v0 : 0.f;
        float v1 = acc[i][j][1] + bb[1]; v1 = v1 > 0.f ? v1 : 0.f;
        float v2 = acc[i][j][2] + bb[2]; v2 = v2 > 0.f ? v2 : 0.f;
        float v3 = acc[i][j][3] + bb[3]; v3 = v3 > 0.f ? v3 : 0.f;
        u32x2 pk; pk[0] = cvtpk(v0, v1); pk[1] = cvtpk(v2, v3);
        if (edge < cnt) *(u32x2*)&h2s[(ts + edge) * 128 + chb] = pk;
      }
    }
  }
}

// ---------------- node MLP: persistent blocks, weights staged once ----------------
__launch_bounds__(512, 1)
__global__ void k_node(const u16* __restrict__ x0b, const float* __restrict__ xf,
                       const u16* __restrict__ h2s,
                       const u16* __restrict__ nw1t, const u16* __restrict__ nw2t,
                       const float* __restrict__ nb1, const float* __restrict__ nb2,
                       const int* __restrict__ bstart,
                       const int* __restrict__ nidx, const int* __restrict__ hist_nt,
                       float* __restrict__ out)
{
  const int ty    = blockIdx.y;
  const int cnt0  = hist_nt[0];
  const int cnt_t = ty ? (N_NODES - cnt0) : cnt0;
  const int base_t = ty ? cnt0 : 0;

  __shared__ u16 sNIN[64 * 264];
  __shared__ u16 sNW1[128 * 264];
  __shared__ u16 sNW2[128 * 136];
  __shared__ float sNb1[128];
  __shared__ float sNb2[128];
  __shared__ int sNid[64];

  const int tid  = threadIdx.x;
  const int lane = tid & 63;
  const int wid  = tid >> 6;
  const int llo  = lane & 15;
  const int lhi  = lane >> 4;

  for (int i = tid; i < 128 * 256; i += 512) {
    int n = i >> 8, k = i & 255;
    sNW1[n * 264 + k] = nw1t[(ty * 128 + n) * 256 + k];
  }
  for (int i = tid; i < 128 * 128; i += 512) {
    int n = i >> 7, k = i & 127;
    sNW2[n * 136 + k] = nw2t[(ty * 128 + n) * 128 + k];
  }
  if (tid < 128) { sNb1[tid] = nb1[ty * 128 + tid]; sNb2[tid] = nb2[ty * 128 + tid]; }
  __syncthreads();

  for (int t0 = blockIdx.x * 64; t0 < cnt_t; t0 += 128 * 64) {
    const int cnt = min(64, cnt_t - t0);
    if (tid < 64) {
      int nid = 0;
      if (tid < cnt) nid = nidx[base_t + t0 + tid];
      sNid[tid] = nid;
    }
    __syncthreads();

    // stage node_in: x part + agg (sum of two contiguous h2 runs); 8 threads/node
    {
      const int m = tid >> 3, qq = tid & 7;
      const int nid = sNid[m];
      const u16* xs = &x0b[nid * 128 + qq * 16];
      u16* dst = &sNIN[m * 264 + qq * 16];
      #pragma unroll
      for (int j = 0; j < 2; ++j) *(u32x4*)(dst + j * 8) = *(const u32x4*)(xs + j * 8);

      float a[16];
      #pragma unroll
      for (int j = 0; j < 16; ++j) a[j] = 0.f;
      #pragma unroll
      for (int pr = 0; pr < 2; ++pr) {
        const int key = (ty * 2 + pr) * N_NODES + nid;
        const int s = bstart[key], e = bstart[key + 1];
        for (int pos = s; pos < e; ++pos) {
          const u16* hp = &h2s[pos * 128 + qq * 16];
          #pragma unroll
          for (int j = 0; j < 2; ++j) {
            u32x4 v = *(const u32x4*)(hp + j * 8);
            #pragma unroll
            for (int w = 0; w < 4; ++w) {
              unsigned uu = v[w];
              a[j * 8 + w * 2 + 0] += b2f((u16)(uu & 0xFFFFu));
              a[j * 8 + w * 2 + 1] += b2f((u16)(uu >> 16));
            }
          }
        }
      }
      u16* ad = &sNIN[m * 264 + 128 + qq * 16];
      #pragma unroll
      for (int j = 0; j < 8; ++j) {
        unsigned pk = cvtpk(a[2 * j], a[2 * j + 1]);
        *(unsigned*)(ad + 2 * j) = pk;
      }
    }
    __syncthreads();

    // layer 1: (64 x 256) @ (256 x 128); wave = 64 rows x 16 cols
    f32x4 acc[4];
    #pragma unroll
    for (int i = 0; i < 4; ++i) acc[i] = (f32x4){0.f, 0.f, 0.f, 0.f};

    #pragma unroll
    for (int ck = 0; ck < 8; ++ck) {
      const int kk = ck * 32 + lhi * 8;
      bf16x8 a[4], b;
      #pragma unroll
      for (int i = 0; i < 4; ++i)
        a[i] = *(const bf16x8*)&sNIN[(i * 16 + llo) * 264 + kk];
      b = *(const bf16x8*)&sNW1[(wid * 16 + llo) * 264 + kk];
      #pragma unroll
      for (int i = 0; i < 4; ++i)
        acc[i] = __builtin_amdgcn_mfma_f32_16x16x32_bf16(a[i], b, acc[i], 0, 0, 0);
    }
    __syncthreads();

    u16* sH1 = sNIN;  // reuse (stride 136)
    #pragma unroll
    for (int i = 0; i < 4; ++i) {
      const int c = wid * 16 + llo;
      const float bias = sNb1[c];
      #pragma unroll
      for (int r = 0; r < 4; ++r) {
        const int m = i * 16 + lhi * 4 + r;
        float v = acc[i][r] + bias;
        v = v > 0.f ? v : 0.f;
        sH1[m * 136 + c] = f2b(v);
      }
    }
    __syncthreads();

    #pragma unroll
    for (int i = 0; i < 4; ++i) acc[i] = (f32x4){0.f, 0.f, 0.f, 0.f};

    #pragma unroll
    for (int ck = 0; ck < 4; ++ck) {
      const int kk = ck * 32 + lhi * 8;
      bf16x8 a[4], b;
      #pragma unroll
      for (int i = 0; i < 4; ++i)
        a[i] = *(const bf16x8*)&sH1[(i * 16 + llo) * 136 + kk];
      b = *(const bf16x8*)&sNW2[(wid * 16 + llo) * 136 + kk];
      #pragma unroll
      for (int i = 0; i < 4; ++i)
        acc[i] = __builtin_amdgcn_mfma_f32_16x16x32_bf16(a[i], b, acc[i], 0, 0, 0);
    }

    #pragma unroll
    for (int i = 0; i < 4; ++i) {
      const int c = wid * 16 + llo;
      const float bias = sNb2[c];
      #pragma unroll
      for (int r = 0; r < 4; ++r) {
        const int m = i * 16 + lhi * 4 + r;
        if (m < cnt) {
          const int nid = sNid[m];
          out[nid * 128 + c] = acc[i][r] + bias + xf[nid * 128 + c];
        }
      }
    }
    __syncthreads();
  }
}

// ---------------- launch ----------------
extern "C" void kernel_launch(void* const* d_in, const int* in_sizes, int n_in,
                              void* d_out, int out_size, void* d_ws, size_t ws_size,
                              hipStream_t stream)
{
  const float* x   = (const float*)d_in[0];
  const int*   ei  = (const int*)d_in[1];
  const float* ea  = (const float*)d_in[2];
  const int*   ntp = (const int*)d_in[3];
  const float* ew1 = (const float*)d_in[4];
  const float* eb1 = (const float*)d_in[5];
  const float* ew2 = (const float*)d_in[6];
  const float* eb2 = (const float*)d_in[7];
  const float* nw1 = (const float*)d_in[8];
  const float* nb1 = (const float*)d_in[9];
  const float* nw2 = (const float*)d_in[10];
  const float* nb2 = (const float*)d_in[11];

  char* ws = (char*)d_ws;
  int*  hist    = (int*)(ws + 0);          // 320000
  int*  hist_nt = (int*)(ws + 320000);     // 8
  int*  cur_nt  = (int*)(ws + 320008);     // 8
  int*  parts   = (int*)(ws + 320256);     // 1252
  int*  bstart  = (int*)(ws + 321792);     // 320004
  u16*  srank   = (u16*)(ws + 641824);     // 640000
  int2* sedge   = (int2*)(ws + 1281824);   // 2560000
  int*  nidx    = (int*)(ws + 3841824);    // 80000
  u16*  x0b     = (u16*)(ws + 3921824);    // 5120000
  u16*  wt1t    = (u16*)(ws + 9041824);    // 294912
  u16*  wt2t    = (u16*)(ws + 9336736);    // 131072
  u16*  nw1t    = (u16*)(ws + 9467808);    // 131072
  u16*  nw2t    = (u16*)(ws + 9598880);    // 65536
  u16*  h2s     = (u16*)(ws + 9664416);    // 81920000 -> total ~91.6 MB

  hipMemsetAsync(ws, 0, 320016, stream);
  k_preconv<<<11216, 256, 0, stream>>>(x, ew1, ew2, nw1, nw2, x0b, wt1t, wt2t, nw1t, nw2t);
  k_hist<<<1250, 256, 0, stream>>>(ei, ntp, hist, hist_nt, srank);
  k_scan1<<<SCAN_NBLK, 256, 0, stream>>>(hist, parts);
  k_scan2<<<1, 512, 0, stream>>>(parts);
  k_scan3<<<SCAN_NBLK, 256, 0, stream>>>(hist, parts, bstart);
  k_place<<<1250, 256, 0, stream>>>(ei, ntp, srank, bstart, sedge, cur_nt, hist_nt, nidx);
  k_edge<<<dim3(64, 4), 512, 0, stream>>>(x0b, ea, wt1t, wt2t, eb1, eb2, bstart, sedge, h2s);
  k_node<<<dim3(128, 2), 512, 0, stream>>>(x0b, x, h2s, nw1t, nw2t, nb1, nb2, bstart, nidx, hist_nt, (float*)d_out);
}